// Round 1
// 1302.711 us; speedup vs baseline: 2.2154x; 2.2154x over previous
//
#include <hip/hip_runtime.h>

// Packed-sequence GRU decoder + fused log_softmax head, MFMA formulation.
// T=512, B=1024, V=64, H=100.
//
// 64 blocks x 256 threads; block owns 16 batch rows (one MFMA M-tile).
// Gate pre-activations per step via mfma_f32_16x16x32_f16:
//   C[16 rows][gate tile] = A[16][K] @ B[K][gate],  A = x_t (K=64) then h (K=128 pad)
// Weights live in per-wave registers as B-fragments (static across t).
// h_t lives in fp32 registers (owner = its C-slot thread) and is published
// to LDS each step as f16 hi + f16 lo (split-float: ~fp32-accurate h GEMM).
// Bias trick: h-fragment column k=100 is constant 1.0; W_hh fragment k=100
// carries (b_ih+b_hh) for r/z sections, b_hh for n; b_ih(n) added in pointwise.
// Head (logits + log_softmax for step t-1) piggybacks on step t's h-fragment
// reads: 8 extra MFMAs + 16-lane-group shuffle softmax; out_head kernel gone.

#define T_STEPS 512
#define BATCH   1024
#define VOCAB   64
#define HID     100
#define BB      16      // batch rows per block
#define NKH     4       // h k-steps  (K = 128, padded; k==100 is bias column)
#define NKX     2       // x k-steps  (K = 64)
#define HSTR    136     // f16 row stride for h fragment buffers (128 + 8 pad)
#define LSTR    68      // f32 row stride for logits buffer

typedef _Float16 f16;
typedef _Float16 f16x8 __attribute__((ext_vector_type(8)));
typedef float    f32x4 __attribute__((ext_vector_type(4)));

#define MFMA(A_, B_, C_) __builtin_amdgcn_mfma_f32_16x16x32_f16((A_), (B_), (C_), 0, 0, 0)

__device__ __forceinline__ float sigm(float v)   { return 1.0f / (1.0f + __expf(-v)); }
__device__ __forceinline__ float tanh_f(float v) { return 1.0f - 2.0f / (__expf(2.0f * v) + 1.0f); }

__global__ __launch_bounds__(256, 1) void gru_mfma(
    const float* __restrict__ x, const float* __restrict__ h0,
    const int* __restrict__ lengths,
    const float* __restrict__ W_ih, const float* __restrict__ W_hh,
    const float* __restrict__ b_ih, const float* __restrict__ b_hh,
    const float* __restrict__ W_out, const float* __restrict__ b_out,
    float* __restrict__ out)
{
    const int tid = threadIdx.x;
    const int w   = tid >> 6;        // wave 0..3
    const int l   = tid & 63;
    const int c   = l & 15;          // frag col (A row index / B gate index)
    const int lg  = l >> 4;          // lane group 0..3
    const int rowbase = blockIdx.x * BB;

    __shared__ alignas(16) f16   hHi[BB * HSTR];
    __shared__ alignas(16) f16   hLo[BB * HSTR];
    __shared__ alignas(16) float logitsL[BB * LSTR];
    __shared__ int lensL[BB];

    // ---------------- static per-wave state ----------------
    f16x8 whh[2][3][NKH];   // [qi][section r/z/n][kstep]  B-frags of W_hh^T (+bias col)
    f16x8 wih[2][3][NKX];   // B-frags of W_ih^T
    f16x8 wout[NKH];        // B-frags of W_out^T for vocab tile [16w,16w+16) (+b_out col)
    float bin[2];           // b_ih of n-section for this lane's k
    float hold4[2][4];      // fp32 hidden owned by this thread: (qi, reg)->(row,k)
    int   lenv[4];          // lengths for rows lg*4 + r

    #pragma unroll
    for (int qi = 0; qi < 2; ++qi) {
        const int q  = 2 * w + qi;          // global gate tile 0..7
        const int gl = 16 * q + c;          // gate index within a section
        const bool gv = gl < HID;
        #pragma unroll
        for (int s = 0; s < 3; ++s) {
            const int g = s * HID + gl;     // row of W_* (valid only if gv)
            #pragma unroll
            for (int ks = 0; ks < NKH; ++ks) {
                f16x8 v;
                #pragma unroll
                for (int j = 0; j < 8; ++j) {
                    const int k = ks * 32 + lg * 8 + j;
                    float val = 0.f;
                    if (gv) {
                        if (k < HID)        val = W_hh[(size_t)g * HID + k];
                        else if (k == HID)  val = (s < 2) ? (b_ih[g] + b_hh[g]) : b_hh[g];
                    }
                    v[j] = (f16)val;
                }
                whh[qi][s][ks] = v;
            }
            #pragma unroll
            for (int ks = 0; ks < NKX; ++ks) {
                f16x8 v;
                #pragma unroll
                for (int j = 0; j < 8; ++j) {
                    const int k = ks * 32 + lg * 8 + j;
                    float val = gv ? W_ih[(size_t)g * VOCAB + k] : 0.f;
                    v[j] = (f16)val;
                }
                wih[qi][s][ks] = v;
            }
        }
        bin[qi] = gv ? b_ih[2 * HID + gl] : 0.f;
    }
    {
        const int v0 = 16 * w + c;          // vocab row for head tile
        #pragma unroll
        for (int ks = 0; ks < NKH; ++ks) {
            f16x8 v;
            #pragma unroll
            for (int j = 0; j < 8; ++j) {
                const int k = ks * 32 + lg * 8 + j;
                float val = 0.f;
                if (k < HID)        val = W_out[(size_t)v0 * HID + k];
                else if (k == HID)  val = b_out[v0];
                v[j] = (f16)val;
            }
            wout[ks] = v;
        }
    }

    #pragma unroll
    for (int r = 0; r < 4; ++r) lenv[r] = lengths[rowbase + lg * 4 + r];

    // initial hidden: fp32 registers + hi/lo f16 fragments in LDS
    #pragma unroll
    for (int qi = 0; qi < 2; ++qi) {
        const int kk = 16 * (2 * w + qi) + c;
        #pragma unroll
        for (int r = 0; r < 4; ++r) {
            const int row = lg * 4 + r;
            float hv = (kk < HID) ? h0[(size_t)(rowbase + row) * HID + kk] : 0.f;
            hold4[qi][r] = hv;
            if (kk < HID) {
                f16 hi = (f16)hv;
                hHi[row * HSTR + kk] = hi;
                hLo[row * HSTR + kk] = (f16)(hv - (float)hi);
            }
        }
    }
    if (tid < BB) {
        lensL[tid] = lengths[rowbase + tid];
        #pragma unroll
        for (int k = HID; k < 128; ++k) {
            hHi[tid * HSTR + k] = (f16)0.f;
            hLo[tid * HSTR + k] = (f16)0.f;
        }
        hHi[tid * HSTR + HID] = (f16)1.0f;   // bias column
    }

    // x fragments for t = 0
    f16x8 xf[NKX];
    {
        const float* xp = x + ((size_t)rowbase + c) * VOCAB + lg * 8;
        #pragma unroll
        for (int ks = 0; ks < NKX; ++ks) {
            float4 a = *reinterpret_cast<const float4*>(xp + ks * 32);
            float4 b2 = *reinterpret_cast<const float4*>(xp + ks * 32 + 4);
            f16x8 v;
            v[0] = (f16)a.x;  v[1] = (f16)a.y;  v[2] = (f16)a.z;  v[3] = (f16)a.w;
            v[4] = (f16)b2.x; v[5] = (f16)b2.y; v[6] = (f16)b2.z; v[7] = (f16)b2.w;
            xf[ks] = v;
        }
    }
    __syncthreads();

    for (int t = 0; t < T_STEPS; ++t) {
        // ---------------- phase A: GEMMs ----------------
        // prefetch x(t+1) (consumed in phase B)
        float4 xp0, xp1, xp2, xp3;
        {
            const int tn = (t + 1 < T_STEPS) ? t + 1 : t;
            const float* xp = x + ((size_t)tn * BATCH + rowbase + c) * VOCAB + lg * 8;
            xp0 = *reinterpret_cast<const float4*>(xp);
            xp1 = *reinterpret_cast<const float4*>(xp + 4);
            xp2 = *reinterpret_cast<const float4*>(xp + 32);
            xp3 = *reinterpret_cast<const float4*>(xp + 36);
        }

        f32x4 aR[2], aZ[2], aNX[2], aNH[2];
        f32x4 hacc = {0.f, 0.f, 0.f, 0.f};
        #pragma unroll
        for (int qi = 0; qi < 2; ++qi) {
            f32x4 z4 = {0.f, 0.f, 0.f, 0.f};
            aR[qi] = z4; aZ[qi] = z4; aNX[qi] = z4; aNH[qi] = z4;
        }

        // x-part first (register-only; covers LDS latency of h-frag reads)
        #pragma unroll
        for (int ks = 0; ks < NKX; ++ks) {
            #pragma unroll
            for (int qi = 0; qi < 2; ++qi) {
                aR[qi]  = MFMA(xf[ks], wih[qi][0][ks], aR[qi]);
                aZ[qi]  = MFMA(xf[ks], wih[qi][1][ks], aZ[qi]);
                aNX[qi] = MFMA(xf[ks], wih[qi][2][ks], aNX[qi]);
            }
        }
        // h-part (hi+lo split) + fused head for step t-1
        #pragma unroll
        for (int ks = 0; ks < NKH; ++ks) {
            const int off = c * HSTR + ks * 32 + lg * 8;
            f16x8 hhi = *reinterpret_cast<const f16x8*>(&hHi[off]);
            f16x8 hlo = *reinterpret_cast<const f16x8*>(&hLo[off]);
            #pragma unroll
            for (int qi = 0; qi < 2; ++qi) {
                aR[qi]  = MFMA(hlo, whh[qi][0][ks], aR[qi]);
                aR[qi]  = MFMA(hhi, whh[qi][0][ks], aR[qi]);
                aZ[qi]  = MFMA(hlo, whh[qi][1][ks], aZ[qi]);
                aZ[qi]  = MFMA(hhi, whh[qi][1][ks], aZ[qi]);
                aNH[qi] = MFMA(hlo, whh[qi][2][ks], aNH[qi]);
                aNH[qi] = MFMA(hhi, whh[qi][2][ks], aNH[qi]);
            }
            if (t > 0) {
                hacc = MFMA(hlo, wout[ks], hacc);
                hacc = MFMA(hhi, wout[ks], hacc);
            }
        }
        if (t > 0) {
            #pragma unroll
            for (int r = 0; r < 4; ++r)
                logitsL[(lg * 4 + r) * LSTR + 16 * w + c] = hacc[r];
        }
        __syncthreads();

        // ---------------- phase B: pointwise ----------------
        // log-softmax + store for step t-1 (reads logits written by all waves)
        if (t > 0) {
            const int rowS = 4 * w + lg;
            const int tp = t - 1;
            float4 o;
            if (tp < lensL[rowS]) {
                float4 v = *reinterpret_cast<const float4*>(&logitsL[rowS * LSTR + 4 * c]);
                float m = fmaxf(fmaxf(v.x, v.y), fmaxf(v.z, v.w));
                #pragma unroll
                for (int off = 8; off >= 1; off >>= 1) m = fmaxf(m, __shfl_xor(m, off));
                float e0 = __expf(v.x - m), e1 = __expf(v.y - m);
                float e2 = __expf(v.z - m), e3 = __expf(v.w - m);
                float s = e0 + e1 + e2 + e3;
                #pragma unroll
                for (int off = 8; off >= 1; off >>= 1) s += __shfl_xor(s, off);
                float ls = m + __logf(s);
                o = make_float4(v.x - ls, v.y - ls, v.z - ls, v.w - ls);
            } else {
                o = make_float4(0.f, 0.f, 0.f, 0.f);
            }
            *reinterpret_cast<float4*>(
                out + ((size_t)tp * BATCH + rowbase + 4 * w + lg) * VOCAB + 4 * c) = o;
        }

        // GRU pointwise + publish h_t as hi/lo fragments
        #pragma unroll
        for (int qi = 0; qi < 2; ++qi) {
            const int kk = 16 * (2 * w + qi) + c;
            const bool kv = kk < HID;
            #pragma unroll
            for (int r = 0; r < 4; ++r) {
                float rg = sigm(aR[qi][r]);
                float zg = sigm(aZ[qi][r]);
                float ng = tanh_f(fmaf(rg, aNH[qi][r], aNX[qi][r] + bin[qi]));
                float hnew = fmaf(zg, hold4[qi][r] - ng, ng);   // (1-z)n + z*h
                float hv = (t < lenv[r]) ? hnew : hold4[qi][r];
                hold4[qi][r] = hv;
                if (kv) {
                    const int row = lg * 4 + r;
                    f16 hi = (f16)hv;
                    hHi[row * HSTR + kk] = hi;
                    hLo[row * HSTR + kk] = (f16)(hv - (float)hi);
                }
            }
        }

        // convert prefetched x(t+1) into fragments
        {
            f16x8 v;
            v[0] = (f16)xp0.x; v[1] = (f16)xp0.y; v[2] = (f16)xp0.z; v[3] = (f16)xp0.w;
            v[4] = (f16)xp1.x; v[5] = (f16)xp1.y; v[6] = (f16)xp1.z; v[7] = (f16)xp1.w;
            xf[0] = v;
            v[0] = (f16)xp2.x; v[1] = (f16)xp2.y; v[2] = (f16)xp2.z; v[3] = (f16)xp2.w;
            v[4] = (f16)xp3.x; v[5] = (f16)xp3.y; v[6] = (f16)xp3.z; v[7] = (f16)xp3.w;
            xf[1] = v;
        }
        __syncthreads();
    }

    // ---------------- epilogue: head for t = T-1 ----------------
    {
        f32x4 hacc = {0.f, 0.f, 0.f, 0.f};
        #pragma unroll
        for (int ks = 0; ks < NKH; ++ks) {
            const int off = c * HSTR + ks * 32 + lg * 8;
            f16x8 hhi = *reinterpret_cast<const f16x8*>(&hHi[off]);
            f16x8 hlo = *reinterpret_cast<const f16x8*>(&hLo[off]);
            hacc = MFMA(hlo, wout[ks], hacc);
            hacc = MFMA(hhi, wout[ks], hacc);
        }
        #pragma unroll
        for (int r = 0; r < 4; ++r)
            logitsL[(lg * 4 + r) * LSTR + 16 * w + c] = hacc[r];
        __syncthreads();

        const int rowS = 4 * w + lg;
        const int tp = T_STEPS - 1;
        float4 o;
        if (tp < lensL[rowS]) {
            float4 v = *reinterpret_cast<const float4*>(&logitsL[rowS * LSTR + 4 * c]);
            float m = fmaxf(fmaxf(v.x, v.y), fmaxf(v.z, v.w));
            #pragma unroll
            for (int off = 8; off >= 1; off >>= 1) m = fmaxf(m, __shfl_xor(m, off));
            float e0 = __expf(v.x - m), e1 = __expf(v.y - m);
            float e2 = __expf(v.z - m), e3 = __expf(v.w - m);
            float s = e0 + e1 + e2 + e3;
            #pragma unroll
            for (int off = 8; off >= 1; off >>= 1) s += __shfl_xor(s, off);
            float ls = m + __logf(s);
            o = make_float4(v.x - ls, v.y - ls, v.z - ls, v.w - ls);
        } else {
            o = make_float4(0.f, 0.f, 0.f, 0.f);
        }
        *reinterpret_cast<float4*>(
            out + ((size_t)tp * BATCH + rowbase + 4 * w + lg) * VOCAB + 4 * c) = o;
    }
}

extern "C" void kernel_launch(void* const* d_in, const int* in_sizes, int n_in,
                              void* d_out, int out_size, void* d_ws, size_t ws_size,
                              hipStream_t stream) {
    const float* x     = (const float*)d_in[0];
    const float* h0    = (const float*)d_in[1];
    const int*   lens  = (const int*)  d_in[2];
    const float* W_ih  = (const float*)d_in[3];
    const float* W_hh  = (const float*)d_in[4];
    const float* b_ih  = (const float*)d_in[5];
    const float* b_hh  = (const float*)d_in[6];
    const float* W_out = (const float*)d_in[7];
    const float* b_out = (const float*)d_in[8];
    float* outp = (float*)d_out;

    gru_mfma<<<BATCH / BB, 256, 0, stream>>>(x, h0, lens, W_ih, W_hh,
                                             b_ih, b_hh, W_out, b_out, outp);
}

// Round 2
// 1097.292 us; speedup vs baseline: 2.6302x; 1.1872x over previous
//
#include <hip/hip_runtime.h>

// Packed-sequence GRU decoder + fused log_softmax head, MFMA formulation, v2.
// T=512, B=1024, V=64, H=100.
//
// 64 blocks x 512 threads (8 waves); block owns 16 batch rows (one MFMA M-tile).
// Waves 0..6: gate tile w (16 gate cols x 3 sections r/z/n) via
//   mfma_f32_16x16x32_f16; weights held in registers; h published per step to
//   double-buffered LDS as f16 hi + f16 lo (split-float ~fp32 recurrence).
// Wave 7: the whole output head for h_{t-1}: 4 vocab tiles x (hi+lo) MFMAs,
//   intra-wave log_softmax (shfl within 16-lane groups), coalesced float4 store.
// ONE __syncthreads per step: h double-buffer (read buf[t&1], write buf[t&1^1]);
// head/softmax/store has no cross-wave dependency.
// Bias trick: h-fragment column k=100 is constant 1.0; W_hh fragment k=100
// carries (b_ih+b_hh) for r/z, b_hh for n (b_ih(n) added scalar); W_out k=100
// carries b_out.

#define T_STEPS 512
#define BATCH   1024
#define VOCAB   64
#define HID     100
#define BB      16      // batch rows per block (MFMA M)
#define NKH     4       // h k-steps (K=128 padded; k==100 is bias column)
#define NKX     2       // x k-steps (K=64)
#define HSTR    136     // f16 row stride for h fragment buffers
#define LSTR    68      // f32 row stride for logits buffer (wave-7 private)

typedef _Float16 f16;
typedef _Float16 f16x8 __attribute__((ext_vector_type(8)));
typedef float    f32x4 __attribute__((ext_vector_type(4)));

#define MFMA(A_, B_, C_) __builtin_amdgcn_mfma_f32_16x16x32_f16((A_), (B_), (C_), 0, 0, 0)

__device__ __forceinline__ float sigm(float v)   { return 1.0f / (1.0f + __expf(-v)); }
__device__ __forceinline__ float tanh_f(float v) { return 1.0f - 2.0f / (__expf(2.0f * v) + 1.0f); }

__global__ __launch_bounds__(512, 2) void gru_mfma(
    const float* __restrict__ x, const float* __restrict__ h0,
    const int* __restrict__ lengths,
    const float* __restrict__ W_ih, const float* __restrict__ W_hh,
    const float* __restrict__ b_ih, const float* __restrict__ b_hh,
    const float* __restrict__ W_out, const float* __restrict__ b_out,
    float* __restrict__ out)
{
    const int tid = threadIdx.x;
    const int w   = tid >> 6;        // wave 0..7
    const int l   = tid & 63;
    const int c   = l & 15;          // frag col (A batch-row / B gate or vocab col)
    const int lg  = l >> 4;          // lane group 0..3
    const int rowbase = blockIdx.x * BB;

    __shared__ alignas(16) f16   hHi[2][BB * HSTR];
    __shared__ alignas(16) f16   hLo[2][BB * HSTR];
    __shared__ alignas(16) float logitsL[BB * LSTR];   // wave-7 private
    __shared__ int lensL[BB];

    // Union'd weight fragments:
    //   waves 0..6: wf[s*4+ks] = W_hh^T frags (s=r/z/n; +bias col k=100)
    //               wf[12+s*2+ks] = W_ih^T frags
    //   wave 7:     wf[v*4+ks] = W_out^T frags for vocab tile v (+b_out col)
    f16x8 wf[18];
    float bin = 0.f;        // b_ih(n) for this lane's gate col
    float hold4[4];         // fp32 hidden owned by this thread (rows lg*4+r)
    int   lenv[4];

    #pragma unroll
    for (int r = 0; r < 4; ++r) lenv[r] = lengths[rowbase + lg * 4 + r];

    if (w < 7) {
        const int gl = 16 * w + c;
        const bool gv = gl < HID;
        #pragma unroll
        for (int s = 0; s < 3; ++s) {
            const int g = s * HID + gl;
            #pragma unroll
            for (int ks = 0; ks < NKH; ++ks) {
                f16x8 v;
                #pragma unroll
                for (int j = 0; j < 8; ++j) {
                    const int k = ks * 32 + lg * 8 + j;
                    float val = 0.f;
                    if (gv) {
                        if (k < HID)        val = W_hh[(size_t)g * HID + k];
                        else if (k == HID)  val = (s < 2) ? (b_ih[g] + b_hh[g]) : b_hh[g];
                    }
                    v[j] = (f16)val;
                }
                wf[s * 4 + ks] = v;
            }
            #pragma unroll
            for (int ks = 0; ks < NKX; ++ks) {
                f16x8 v;
                #pragma unroll
                for (int j = 0; j < 8; ++j) {
                    const int k = ks * 32 + lg * 8 + j;
                    v[j] = (f16)(gv ? W_ih[(size_t)g * VOCAB + k] : 0.f);
                }
                wf[12 + s * 2 + ks] = v;
            }
        }
        bin = gv ? b_ih[2 * HID + gl] : 0.f;

        // initial hidden: fp32 regs + hi/lo frags into buffer 0
        #pragma unroll
        for (int r = 0; r < 4; ++r) {
            const int row = lg * 4 + r;
            float hv = gv ? h0[(size_t)(rowbase + row) * HID + gl] : 0.f;
            hold4[r] = hv;
            if (gv) {
                f16 hi = (f16)hv;
                hHi[0][row * HSTR + gl] = hi;
                hLo[0][row * HSTR + gl] = (f16)(hv - (float)hi);
            }
        }
    } else {
        #pragma unroll
        for (int vt = 0; vt < 4; ++vt) {
            const int vr = 16 * vt + c;      // vocab row of W_out
            #pragma unroll
            for (int ks = 0; ks < NKH; ++ks) {
                f16x8 v;
                #pragma unroll
                for (int j = 0; j < 8; ++j) {
                    const int k = ks * 32 + lg * 8 + j;
                    float val = 0.f;
                    if (k < HID)        val = W_out[(size_t)vr * HID + k];
                    else if (k == HID)  val = b_out[vr];
                    v[j] = (f16)val;
                }
                wf[vt * 4 + ks] = v;
            }
        }
        hold4[0] = hold4[1] = hold4[2] = hold4[3] = 0.f;
    }

    if (tid < BB) {
        lensL[tid] = lengths[rowbase + tid];
        #pragma unroll
        for (int k = HID; k < 128; ++k) {
            hHi[0][tid * HSTR + k] = (f16)0.f;  hLo[0][tid * HSTR + k] = (f16)0.f;
            hHi[1][tid * HSTR + k] = (f16)0.f;  hLo[1][tid * HSTR + k] = (f16)0.f;
        }
        hHi[0][tid * HSTR + HID] = (f16)1.0f;   // bias column (both buffers)
        hHi[1][tid * HSTR + HID] = (f16)1.0f;
    }

    // x fragments for t = 0 (gate waves only)
    f16x8 xf[NKX];
    if (w < 7) {
        const float* xp = x + ((size_t)rowbase + c) * VOCAB + lg * 8;
        #pragma unroll
        for (int ks = 0; ks < NKX; ++ks) {
            float4 a  = *reinterpret_cast<const float4*>(xp + ks * 32);
            float4 b2 = *reinterpret_cast<const float4*>(xp + ks * 32 + 4);
            f16x8 v;
            v[0] = (f16)a.x;  v[1] = (f16)a.y;  v[2] = (f16)a.z;  v[3] = (f16)a.w;
            v[4] = (f16)b2.x; v[5] = (f16)b2.y; v[6] = (f16)b2.z; v[7] = (f16)b2.w;
            xf[ks] = v;
        }
    }
    __syncthreads();

    // Loop runs one extra iteration: gate waves act for t<T, head wave for t>0.
    for (int t = 0; t <= T_STEPS; ++t) {
        const int cur = t & 1;               // buf[cur] holds h_{t-1}
        if (w < 7) {
            if (t < T_STEPS) {
                // prefetch x(t+1)
                const int tn = (t + 1 < T_STEPS) ? t + 1 : t;
                const float* xp = x + ((size_t)tn * BATCH + rowbase + c) * VOCAB + lg * 8;
                float4 xp0 = *reinterpret_cast<const float4*>(xp);
                float4 xp1 = *reinterpret_cast<const float4*>(xp + 4);
                float4 xp2 = *reinterpret_cast<const float4*>(xp + 32);
                float4 xp3 = *reinterpret_cast<const float4*>(xp + 36);

                // h fragments (issued early; x-part MFMAs cover the latency)
                f16x8 hh[NKH], hl[NKH];
                #pragma unroll
                for (int ks = 0; ks < NKH; ++ks) {
                    const int off = c * HSTR + ks * 32 + lg * 8;
                    hh[ks] = *reinterpret_cast<const f16x8*>(&hHi[cur][off]);
                    hl[ks] = *reinterpret_cast<const f16x8*>(&hLo[cur][off]);
                }

                f32x4 aR = {0.f,0.f,0.f,0.f}, aZ = aR, aNX = aR, aNH = aR;
                #pragma unroll
                for (int ks = 0; ks < NKX; ++ks) {
                    aR  = MFMA(xf[ks], wf[12 + ks], aR);
                    aZ  = MFMA(xf[ks], wf[14 + ks], aZ);
                    aNX = MFMA(xf[ks], wf[16 + ks], aNX);
                }
                #pragma unroll
                for (int ks = 0; ks < NKH; ++ks) {
                    aR  = MFMA(hl[ks], wf[0 + ks], aR);
                    aR  = MFMA(hh[ks], wf[0 + ks], aR);
                    aZ  = MFMA(hl[ks], wf[4 + ks], aZ);
                    aZ  = MFMA(hh[ks], wf[4 + ks], aZ);
                    aNH = MFMA(hl[ks], wf[8 + ks], aNH);
                    aNH = MFMA(hh[ks], wf[8 + ks], aNH);
                }

                // pointwise + publish h_t into buf[cur^1]
                const int kk = 16 * w + c;
                const bool kv = kk < HID;
                #pragma unroll
                for (int r = 0; r < 4; ++r) {
                    float rg   = sigm(aR[r]);
                    float zg   = sigm(aZ[r]);
                    float ng   = tanh_f(fmaf(rg, aNH[r], aNX[r] + bin));
                    float hnew = fmaf(zg, hold4[r] - ng, ng);   // (1-z)n + z*h
                    float hv   = (t < lenv[r]) ? hnew : hold4[r];
                    hold4[r] = hv;
                    if (kv) {
                        const int row = lg * 4 + r;
                        f16 hi = (f16)hv;
                        hHi[cur ^ 1][row * HSTR + kk] = hi;
                        hLo[cur ^ 1][row * HSTR + kk] = (f16)(hv - (float)hi);
                    }
                }

                // convert prefetched x(t+1)
                f16x8 v;
                v[0] = (f16)xp0.x; v[1] = (f16)xp0.y; v[2] = (f16)xp0.z; v[3] = (f16)xp0.w;
                v[4] = (f16)xp1.x; v[5] = (f16)xp1.y; v[6] = (f16)xp1.z; v[7] = (f16)xp1.w;
                xf[0] = v;
                v[0] = (f16)xp2.x; v[1] = (f16)xp2.y; v[2] = (f16)xp2.z; v[3] = (f16)xp2.w;
                v[4] = (f16)xp3.x; v[5] = (f16)xp3.y; v[6] = (f16)xp3.z; v[7] = (f16)xp3.w;
                xf[1] = v;
            }
        } else {
            if (t > 0) {
                // head over h_{t-1} (buf[cur]) -> output row t-1
                const int tp = t - 1;
                f16x8 hh[NKH], hl[NKH];
                #pragma unroll
                for (int ks = 0; ks < NKH; ++ks) {
                    const int off = c * HSTR + ks * 32 + lg * 8;
                    hh[ks] = *reinterpret_cast<const f16x8*>(&hHi[cur][off]);
                    hl[ks] = *reinterpret_cast<const f16x8*>(&hLo[cur][off]);
                }
                f32x4 acc0 = {0.f,0.f,0.f,0.f}, acc1 = acc0, acc2 = acc0, acc3 = acc0;
                #pragma unroll
                for (int ks = 0; ks < NKH; ++ks) {
                    acc0 = MFMA(hl[ks], wf[0  + ks], acc0);
                    acc0 = MFMA(hh[ks], wf[0  + ks], acc0);
                    acc1 = MFMA(hl[ks], wf[4  + ks], acc1);
                    acc1 = MFMA(hh[ks], wf[4  + ks], acc1);
                    acc2 = MFMA(hl[ks], wf[8  + ks], acc2);
                    acc2 = MFMA(hh[ks], wf[8  + ks], acc2);
                    acc3 = MFMA(hl[ks], wf[12 + ks], acc3);
                    acc3 = MFMA(hh[ks], wf[12 + ks], acc3);
                }
                // intra-wave log_softmax per row (16-lane groups share a row set)
                #pragma unroll
                for (int r = 0; r < 4; ++r) {
                    float m = fmaxf(fmaxf(acc0[r], acc1[r]), fmaxf(acc2[r], acc3[r]));
                    #pragma unroll
                    for (int off = 8; off >= 1; off >>= 1) m = fmaxf(m, __shfl_xor(m, off));
                    float s = __expf(acc0[r] - m) + __expf(acc1[r] - m)
                            + __expf(acc2[r] - m) + __expf(acc3[r] - m);
                    #pragma unroll
                    for (int off = 8; off >= 1; off >>= 1) s += __shfl_xor(s, off);
                    float ls = m + __logf(s);
                    const int row = lg * 4 + r;
                    logitsL[row * LSTR +      c] = acc0[r] - ls;
                    logitsL[row * LSTR + 16 + c] = acc1[r] - ls;
                    logitsL[row * LSTR + 32 + c] = acc2[r] - ls;
                    logitsL[row * LSTR + 48 + c] = acc3[r] - ls;
                }
                // coalesced masked store (wave-private LDS bounce, no barrier)
                #pragma unroll
                for (int j = 0; j < 4; ++j) {
                    const int row4 = 4 * j + lg;
                    float4 v4 = *reinterpret_cast<const float4*>(&logitsL[row4 * LSTR + c * 4]);
                    if (tp >= lensL[row4]) v4 = make_float4(0.f, 0.f, 0.f, 0.f);
                    *reinterpret_cast<float4*>(
                        out + ((size_t)tp * BATCH + rowbase + row4) * VOCAB + c * 4) = v4;
                }
            }
        }
        __syncthreads();
    }
}

extern "C" void kernel_launch(void* const* d_in, const int* in_sizes, int n_in,
                              void* d_out, int out_size, void* d_ws, size_t ws_size,
                              hipStream_t stream) {
    const float* x     = (const float*)d_in[0];
    const float* h0    = (const float*)d_in[1];
    const int*   lens  = (const int*)  d_in[2];
    const float* W_ih  = (const float*)d_in[3];
    const float* W_hh  = (const float*)d_in[4];
    const float* b_ih  = (const float*)d_in[5];
    const float* b_hh  = (const float*)d_in[6];
    const float* W_out = (const float*)d_in[7];
    const float* b_out = (const float*)d_in[8];
    float* outp = (float*)d_out;

    gru_mfma<<<BATCH / BB, 512, 0, stream>>>(x, h0, lens, W_ih, W_hh,
                                             b_ih, b_hh, W_out, b_out, outp);
}

// Round 3
// 1077.362 us; speedup vs baseline: 2.6788x; 1.0185x over previous
//
#include <hip/hip_runtime.h>

// Packed-sequence GRU decoder + fused log_softmax head, MFMA formulation, v3.
// T=512, B=1024, V=64, H=100.
//
// 64 blocks x 512 threads (8 waves); block owns 16 batch rows (one MFMA M-tile).
// Waves 0..6: gate tile w (16 gate cols x 3 sections r/z/n) via
//   mfma_f32_16x16x32_f16; weights in registers; h published per step to
//   double-buffered LDS as f16 hi + f16 lo (split-float ~fp32 recurrence).
// Wave 7: output head for h_{t-1}: 4 vocab tiles (hi+lo), intra-wave
//   log_softmax, scattered-but-64B-coalesced dword stores (no LDS bounce).
//
// v3 changes (latency attack):
//  * barrier = raw s_waitcnt lgkmcnt(0) + s_barrier -- does NOT drain vmcnt,
//    so the head's global stores and the gate waves' x prefetch loads stay in
//    flight across the step boundary (only LDS has cross-wave deps).
//  * hi/lo MFMA chains split into separate accumulators (max dep depth 10->6).
//  * v_rcp_f32 (rcpf builtin) replaces IEEE divides in sigmoid/tanh.

#define T_STEPS 512
#define BATCH   1024
#define VOCAB   64
#define HID     100
#define BB      16      // batch rows per block (MFMA M)
#define NKH     4       // h k-steps (K=128 padded; k==100 is bias column)
#define NKX     2       // x k-steps (K=64)
#define HSTR    136     // f16 row stride for h fragment buffers

typedef _Float16 f16;
typedef _Float16 f16x8 __attribute__((ext_vector_type(8)));
typedef float    f32x4 __attribute__((ext_vector_type(4)));

#define MFMA(A_, B_, C_) __builtin_amdgcn_mfma_f32_16x16x32_f16((A_), (B_), (C_), 0, 0, 0)

__device__ __forceinline__ float rcp_f(float v)  { return __builtin_amdgcn_rcpf(v); }
__device__ __forceinline__ float sigm(float v)   { return rcp_f(1.0f + __expf(-v)); }
__device__ __forceinline__ float tanh_f(float v) { return 1.0f - 2.0f * rcp_f(__expf(2.0f * v) + 1.0f); }

// Barrier that only orders LDS: no vmcnt(0) drain (global stores/loads may
// stay in flight -- nothing cross-wave depends on them).
__device__ __forceinline__ void sync_lds() {
    __builtin_amdgcn_sched_barrier(0);
    asm volatile("s_waitcnt lgkmcnt(0)" ::: "memory");
    __builtin_amdgcn_s_barrier();
    __builtin_amdgcn_sched_barrier(0);
}

__global__ __launch_bounds__(512, 2) void gru_mfma(
    const float* __restrict__ x, const float* __restrict__ h0,
    const int* __restrict__ lengths,
    const float* __restrict__ W_ih, const float* __restrict__ W_hh,
    const float* __restrict__ b_ih, const float* __restrict__ b_hh,
    const float* __restrict__ W_out, const float* __restrict__ b_out,
    float* __restrict__ out)
{
    const int tid = threadIdx.x;
    const int w   = tid >> 6;        // wave 0..7
    const int l   = tid & 63;
    const int c   = l & 15;          // frag col (A batch-row / B gate or vocab col)
    const int lg  = l >> 4;          // lane group 0..3
    const int rowbase = blockIdx.x * BB;

    __shared__ alignas(16) f16 hHi[2][BB * HSTR];
    __shared__ alignas(16) f16 hLo[2][BB * HSTR];

    // Union'd weight fragments:
    //   waves 0..6: wf[s*4+ks] = W_hh^T frags (s=r/z/n; +bias col k=100)
    //               wf[12+s*2+ks] = W_ih^T frags
    //   wave 7:     wf[v*4+ks] = W_out^T frags for vocab tile v (+b_out col)
    f16x8 wf[18];
    float bin = 0.f;        // b_ih(n) for this lane's gate col
    float hold4[4];         // fp32 hidden owned by this thread (rows lg*4+r)
    int   lenv[4];

    #pragma unroll
    for (int r = 0; r < 4; ++r) lenv[r] = lengths[rowbase + lg * 4 + r];

    if (w < 7) {
        const int gl = 16 * w + c;
        const bool gv = gl < HID;
        #pragma unroll
        for (int s = 0; s < 3; ++s) {
            const int g = s * HID + gl;
            #pragma unroll
            for (int ks = 0; ks < NKH; ++ks) {
                f16x8 v;
                #pragma unroll
                for (int j = 0; j < 8; ++j) {
                    const int k = ks * 32 + lg * 8 + j;
                    float val = 0.f;
                    if (gv) {
                        if (k < HID)        val = W_hh[(size_t)g * HID + k];
                        else if (k == HID)  val = (s < 2) ? (b_ih[g] + b_hh[g]) : b_hh[g];
                    }
                    v[j] = (f16)val;
                }
                wf[s * 4 + ks] = v;
            }
            #pragma unroll
            for (int ks = 0; ks < NKX; ++ks) {
                f16x8 v;
                #pragma unroll
                for (int j = 0; j < 8; ++j) {
                    const int k = ks * 32 + lg * 8 + j;
                    v[j] = (f16)(gv ? W_ih[(size_t)g * VOCAB + k] : 0.f);
                }
                wf[12 + s * 2 + ks] = v;
            }
        }
        bin = gv ? b_ih[2 * HID + gl] : 0.f;

        // initial hidden: fp32 regs + hi/lo frags into buffer 0
        #pragma unroll
        for (int r = 0; r < 4; ++r) {
            const int row = lg * 4 + r;
            float hv = gv ? h0[(size_t)(rowbase + row) * HID + gl] : 0.f;
            hold4[r] = hv;
            if (gv) {
                f16 hi = (f16)hv;
                hHi[0][row * HSTR + gl] = hi;
                hLo[0][row * HSTR + gl] = (f16)(hv - (float)hi);
            }
        }
    } else {
        #pragma unroll
        for (int vt = 0; vt < 4; ++vt) {
            const int vr = 16 * vt + c;      // vocab row of W_out
            #pragma unroll
            for (int ks = 0; ks < NKH; ++ks) {
                f16x8 v;
                #pragma unroll
                for (int j = 0; j < 8; ++j) {
                    const int k = ks * 32 + lg * 8 + j;
                    float val = 0.f;
                    if (k < HID)        val = W_out[(size_t)vr * HID + k];
                    else if (k == HID)  val = b_out[vr];
                    v[j] = (f16)val;
                }
                wf[vt * 4 + ks] = v;
            }
        }
        hold4[0] = hold4[1] = hold4[2] = hold4[3] = 0.f;
    }

    if (tid < BB) {
        #pragma unroll
        for (int k = HID; k < 128; ++k) {
            hHi[0][tid * HSTR + k] = (f16)0.f;  hLo[0][tid * HSTR + k] = (f16)0.f;
            hHi[1][tid * HSTR + k] = (f16)0.f;  hLo[1][tid * HSTR + k] = (f16)0.f;
        }
        hHi[0][tid * HSTR + HID] = (f16)1.0f;   // bias column (both buffers)
        hHi[1][tid * HSTR + HID] = (f16)1.0f;
    }

    // x fragments for t = 0 (gate waves only)
    f16x8 xf[NKX];
    if (w < 7) {
        const float* xp = x + ((size_t)rowbase + c) * VOCAB + lg * 8;
        #pragma unroll
        for (int ks = 0; ks < NKX; ++ks) {
            float4 a  = *reinterpret_cast<const float4*>(xp + ks * 32);
            float4 b2 = *reinterpret_cast<const float4*>(xp + ks * 32 + 4);
            f16x8 v;
            v[0] = (f16)a.x;  v[1] = (f16)a.y;  v[2] = (f16)a.z;  v[3] = (f16)a.w;
            v[4] = (f16)b2.x; v[5] = (f16)b2.y; v[6] = (f16)b2.z; v[7] = (f16)b2.w;
            xf[ks] = v;
        }
    }
    __syncthreads();   // prologue: full barrier once is fine

    // Loop runs one extra iteration: gate waves act for t<T, head wave for t>0.
    for (int t = 0; t <= T_STEPS; ++t) {
        const int cur = t & 1;               // buf[cur] holds h_{t-1}
        if (w < 7) {
            if (t < T_STEPS) {
                // prefetch x(t+1) (never drained at the barrier; waited only
                // by its own consumers below)
                const int tn = (t + 1 < T_STEPS) ? t + 1 : t;
                const float* xp = x + ((size_t)tn * BATCH + rowbase + c) * VOCAB + lg * 8;
                float4 xp0 = *reinterpret_cast<const float4*>(xp);
                float4 xp1 = *reinterpret_cast<const float4*>(xp + 4);
                float4 xp2 = *reinterpret_cast<const float4*>(xp + 32);
                float4 xp3 = *reinterpret_cast<const float4*>(xp + 36);

                // h fragments
                f16x8 hh[NKH], hl[NKH];
                #pragma unroll
                for (int ks = 0; ks < NKH; ++ks) {
                    const int off = c * HSTR + ks * 32 + lg * 8;
                    hh[ks] = *reinterpret_cast<const f16x8*>(&hHi[cur][off]);
                    hl[ks] = *reinterpret_cast<const f16x8*>(&hLo[cur][off]);
                }

                // split accumulators: x->hi chain (depth 6) || lo chain (depth 4)
                f32x4 zz = {0.f, 0.f, 0.f, 0.f};
                f32x4 aRa = zz, aZa = zz, aNX = zz;
                f32x4 aRb = zz, aZb = zz, aNHa = zz, aNHb = zz;
                #pragma unroll
                for (int ks = 0; ks < NKX; ++ks) {
                    aRa = MFMA(xf[ks], wf[12 + ks], aRa);
                    aZa = MFMA(xf[ks], wf[14 + ks], aZa);
                    aNX = MFMA(xf[ks], wf[16 + ks], aNX);
                }
                #pragma unroll
                for (int ks = 0; ks < NKH; ++ks) {
                    aRa  = MFMA(hh[ks], wf[0 + ks], aRa);
                    aRb  = MFMA(hl[ks], wf[0 + ks], aRb);
                    aZa  = MFMA(hh[ks], wf[4 + ks], aZa);
                    aZb  = MFMA(hl[ks], wf[4 + ks], aZb);
                    aNHa = MFMA(hh[ks], wf[8 + ks], aNHa);
                    aNHb = MFMA(hl[ks], wf[8 + ks], aNHb);
                }

                // convert prefetched x(t+1) (independent; overlaps MFMA latency)
                {
                    f16x8 v;
                    v[0] = (f16)xp0.x; v[1] = (f16)xp0.y; v[2] = (f16)xp0.z; v[3] = (f16)xp0.w;
                    v[4] = (f16)xp1.x; v[5] = (f16)xp1.y; v[6] = (f16)xp1.z; v[7] = (f16)xp1.w;
                    xf[0] = v;
                    v[0] = (f16)xp2.x; v[1] = (f16)xp2.y; v[2] = (f16)xp2.z; v[3] = (f16)xp2.w;
                    v[4] = (f16)xp3.x; v[5] = (f16)xp3.y; v[6] = (f16)xp3.z; v[7] = (f16)xp3.w;
                    xf[1] = v;
                }

                // pointwise + publish h_t into buf[cur^1]
                const int kk = 16 * w + c;
                const bool kv = kk < HID;
                #pragma unroll
                for (int r = 0; r < 4; ++r) {
                    float rg   = sigm(aRa[r] + aRb[r]);
                    float zg   = sigm(aZa[r] + aZb[r]);
                    float ng   = tanh_f(fmaf(rg, aNHa[r] + aNHb[r], aNX[r] + bin));
                    float hnew = fmaf(zg, hold4[r] - ng, ng);   // (1-z)n + z*h
                    float hv   = (t < lenv[r]) ? hnew : hold4[r];
                    hold4[r] = hv;
                    if (kv) {
                        const int row = lg * 4 + r;
                        f16 hi = (f16)hv;
                        hHi[cur ^ 1][row * HSTR + kk] = hi;
                        hLo[cur ^ 1][row * HSTR + kk] = (f16)(hv - (float)hi);
                    }
                }
            }
        } else {
            if (t > 0) {
                // head over h_{t-1} (buf[cur]) -> output row t-1
                const int tp = t - 1;
                f16x8 hh[NKH], hl[NKH];
                #pragma unroll
                for (int ks = 0; ks < NKH; ++ks) {
                    const int off = c * HSTR + ks * 32 + lg * 8;
                    hh[ks] = *reinterpret_cast<const f16x8*>(&hHi[cur][off]);
                    hl[ks] = *reinterpret_cast<const f16x8*>(&hLo[cur][off]);
                }
                f32x4 zz = {0.f, 0.f, 0.f, 0.f};
                f32x4 a0h = zz, a1h = zz, a2h = zz, a3h = zz;
                f32x4 a0l = zz, a1l = zz, a2l = zz, a3l = zz;
                #pragma unroll
                for (int ks = 0; ks < NKH; ++ks) {
                    a0h = MFMA(hh[ks], wf[0  + ks], a0h);
                    a0l = MFMA(hl[ks], wf[0  + ks], a0l);
                    a1h = MFMA(hh[ks], wf[4  + ks], a1h);
                    a1l = MFMA(hl[ks], wf[4  + ks], a1l);
                    a2h = MFMA(hh[ks], wf[8  + ks], a2h);
                    a2l = MFMA(hl[ks], wf[8  + ks], a2l);
                    a3h = MFMA(hh[ks], wf[12 + ks], a3h);
                    a3l = MFMA(hl[ks], wf[12 + ks], a3l);
                }
                // intra-wave log_softmax per row; scattered dword stores
                // (64B-contiguous per 16-lane group; never drained at barrier)
                #pragma unroll
                for (int r = 0; r < 4; ++r) {
                    float v0 = a0h[r] + a0l[r];
                    float v1 = a1h[r] + a1l[r];
                    float v2 = a2h[r] + a2l[r];
                    float v3 = a3h[r] + a3l[r];
                    float m = fmaxf(fmaxf(v0, v1), fmaxf(v2, v3));
                    #pragma unroll
                    for (int off = 8; off >= 1; off >>= 1) m = fmaxf(m, __shfl_xor(m, off));
                    float s = __expf(v0 - m) + __expf(v1 - m)
                            + __expf(v2 - m) + __expf(v3 - m);
                    #pragma unroll
                    for (int off = 8; off >= 1; off >>= 1) s += __shfl_xor(s, off);
                    float ls = m + __logf(s);
                    const bool act = tp < lenv[r];
                    float* orow = out + ((size_t)tp * BATCH + rowbase + lg * 4 + r) * VOCAB + c;
                    orow[ 0] = act ? (v0 - ls) : 0.f;
                    orow[16] = act ? (v1 - ls) : 0.f;
                    orow[32] = act ? (v2 - ls) : 0.f;
                    orow[48] = act ? (v3 - ls) : 0.f;
                }
            }
        }
        sync_lds();
    }
}

extern "C" void kernel_launch(void* const* d_in, const int* in_sizes, int n_in,
                              void* d_out, int out_size, void* d_ws, size_t ws_size,
                              hipStream_t stream) {
    const float* x     = (const float*)d_in[0];
    const float* h0    = (const float*)d_in[1];
    const int*   lens  = (const int*)  d_in[2];
    const float* W_ih  = (const float*)d_in[3];
    const float* W_hh  = (const float*)d_in[4];
    const float* b_ih  = (const float*)d_in[5];
    const float* b_hh  = (const float*)d_in[6];
    const float* W_out = (const float*)d_in[7];
    const float* b_out = (const float*)d_in[8];
    float* outp = (float*)d_out;

    gru_mfma<<<BATCH / BB, 512, 0, stream>>>(x, h0, lens, W_ih, W_hh,
                                             b_ih, b_hh, W_out, b_out, outp);
}